// Round 1
// baseline (828.760 us; speedup 1.0000x reference)
//
#include <hip/hip_runtime.h>
#include <hip/hip_bf16.h>
#include <math.h>

typedef unsigned short u16;
typedef unsigned int   u32;
typedef __attribute__((ext_vector_type(8))) short short8;  // 8 bf16 (4 VGPRs) - MFMA A/B frag
typedef __attribute__((ext_vector_type(4))) float f32x4;   // MFMA C/D frag

#define Bn 2
#define Cn 4
#define Fn 512
#define Hn 8
#define Wn 1024
#define DHn 64
#define FW (Fn*Wn)            // 524288 per (b,c)
#define BCFW (Bn*Cn*Fn*Wn)    // 4194304 per tensor

__device__ __forceinline__ u16 f2bf(float f) {
  u32 u = __builtin_bit_cast(u32, f);
  u += 0x7fffu + ((u >> 16) & 1u);   // round-to-nearest-even
  return (u16)(u >> 16);
}
__device__ __forceinline__ float bf2f(u16 h) {
  u32 u = ((u32)h) << 16;
  return __builtin_bit_cast(float, u);
}
__device__ __forceinline__ u32 pack2(u16 a, u16 b) { return (u32)a | ((u32)b << 16); }

// ---------------------------------------------------------------------------
// K0a: convert 4 linear-weight tensors fp32 -> bf16.  wb3 = [q,k,v][C][F][F], wob = [C][F][F]
__global__ __launch_bounds__(256) void wconv_kernel(
    const float* __restrict__ wq, const float* __restrict__ wk,
    const float* __restrict__ wv, const float* __restrict__ wo,
    u16* __restrict__ wb3, u16* __restrict__ wob) {
  int g = blockIdx.x * 256 + threadIdx.x;        // group of 4 elements
  int t = g >> 18;                                // tensor id (2^18 groups = 1M elems each)
  int off = (g & 0x3FFFF) * 4;
  const float* src = (t == 0) ? wq : (t == 1) ? wk : (t == 2) ? wv : wo;
  float4 v = *(const float4*)(src + off);
  u16* dst = (t < 3) ? (wb3 + (size_t)t * 1048576 + off) : (wob + off);
  uint2 p;
  p.x = pack2(f2bf(v.x), f2bf(v.y));
  p.y = pack2(f2bf(v.z), f2bf(v.w));
  *(uint2*)dst = p;
}

// ---------------------------------------------------------------------------
// K0b: x [b,c,f,w] fp32 -> xT [b,c,w,f] bf16 (K-contiguous for gemm_bt B-operand)
__global__ __launch_bounds__(256) void xT_kernel(const float* __restrict__ x, u16* __restrict__ xT) {
  __shared__ __align__(16) u16 T[64 * 72];       // [f_local][w_local], pad 8
  int w0 = blockIdx.x * 64, f0 = blockIdx.y * 64, bc = blockIdx.z;
  int tid = threadIdx.x;
  int r = tid >> 2, g = tid & 3;                  // r: f row, g: 16-col group
  const float* src = x + ((size_t)(bc * Fn + f0 + r)) * Wn + w0 + g * 16;
#pragma unroll
  for (int u = 0; u < 4; u++) {
    float4 v = *(const float4*)(src + u * 4);
    int cb = g * 16 + u * 4;
    T[r * 72 + cb + 0] = f2bf(v.x);
    T[r * 72 + cb + 1] = f2bf(v.y);
    T[r * 72 + cb + 2] = f2bf(v.z);
    T[r * 72 + cb + 3] = f2bf(v.w);
  }
  __syncthreads();
  int wl = tid >> 2, fg = tid & 3;
  u16 ov[16];
#pragma unroll
  for (int u = 0; u < 16; u++) ov[u] = T[(fg * 16 + u) * 72 + wl];
  u16* dst = xT + ((size_t)(bc * Wn + w0 + wl)) * Fn + f0 + fg * 16;
  uint4 o0, o1;
  o0.x = pack2(ov[0], ov[1]);  o0.y = pack2(ov[2], ov[3]);
  o0.z = pack2(ov[4], ov[5]);  o0.w = pack2(ov[6], ov[7]);
  o1.x = pack2(ov[8], ov[9]);  o1.y = pack2(ov[10], ov[11]);
  o1.z = pack2(ov[12], ov[13]); o1.w = pack2(ov[14], ov[15]);
  *(uint4*)(dst) = o0;
  *(uint4*)(dst + 8) = o1;
}

// ---------------------------------------------------------------------------
// GEMM: C[m][n] = sum_k A[m][k]*BT[n][k].  M=512,N=1024,K=512. 128x128 tile, BK=32.
// A = weights base [z][C][512][512]; BT base [bc][1024][512]. Cb bf16 or Cf fp32 out.
__global__ __launch_bounds__(256) void gemm_bt_kernel(
    const u16* __restrict__ Abase, const u16* __restrict__ BTbase,
    u16* __restrict__ Cb, float* __restrict__ Cf) {
  __shared__ __align__(16) u16 As[128 * 40];     // [128][32] pad->40
  __shared__ __align__(16) u16 Bs[128 * 40];
  int tile = blockIdx.x;                          // 0..31
  int bc = blockIdx.y;                            // 0..7 = b*4+c
  int p = blockIdx.z;
  int m0 = (tile & 3) * 128, n0 = (tile >> 2) * 128;
  const u16* A = Abase + ((size_t)(p * 4 + (bc & 3))) * (512 * 512) + (size_t)m0 * 512;
  const u16* BT = BTbase + (size_t)bc * (1024 * 512) + (size_t)n0 * 512;
  int tid = threadIdx.x, wave = tid >> 6, lane = tid & 63;
  int quad = lane >> 4, l16 = lane & 15;
  int wm = (wave >> 1) * 64, wn = (wave & 1) * 64;
  f32x4 acc[4][4];
#pragma unroll
  for (int i = 0; i < 4; i++)
#pragma unroll
    for (int j = 0; j < 4; j++) acc[i][j] = (f32x4){0.f, 0.f, 0.f, 0.f};
  for (int k0 = 0; k0 < 512; k0 += 32) {
    __syncthreads();
    {
      int c0 = tid, c1 = tid + 256;
      int r = c0 >> 2, o = c0 & 3;
      *(uint4*)&As[r * 40 + o * 8] = *(const uint4*)(A + (size_t)r * 512 + k0 + o * 8);
      *(uint4*)&Bs[r * 40 + o * 8] = *(const uint4*)(BT + (size_t)r * 512 + k0 + o * 8);
      r = c1 >> 2; o = c1 & 3;
      *(uint4*)&As[r * 40 + o * 8] = *(const uint4*)(A + (size_t)r * 512 + k0 + o * 8);
      *(uint4*)&Bs[r * 40 + o * 8] = *(const uint4*)(BT + (size_t)r * 512 + k0 + o * 8);
    }
    __syncthreads();
    short8 af[4], bfr[4];
#pragma unroll
    for (int i = 0; i < 4; i++) af[i] = *(const short8*)&As[(wm + i * 16 + l16) * 40 + quad * 8];
#pragma unroll
    for (int j = 0; j < 4; j++) bfr[j] = *(const short8*)&Bs[(wn + j * 16 + l16) * 40 + quad * 8];
#pragma unroll
    for (int i = 0; i < 4; i++)
#pragma unroll
      for (int j = 0; j < 4; j++)
        acc[i][j] = __builtin_amdgcn_mfma_f32_16x16x32_bf16(af[i], bfr[j], acc[i][j], 0, 0, 0);
  }
  size_t coff = (size_t)(Cb ? (p * 8 + bc) : bc) * FW;
#pragma unroll
  for (int i = 0; i < 4; i++)
#pragma unroll
    for (int j = 0; j < 4; j++)
#pragma unroll
      for (int reg = 0; reg < 4; reg++) {
        int row = m0 + wm + i * 16 + quad * 4 + reg;
        int col = n0 + wn + j * 16 + l16;
        if (Cb) Cb[coff + (size_t)row * 1024 + col] = f2bf(acc[i][j][reg]);
        else    Cf[coff + (size_t)row * 1024 + col] = acc[i][j][reg];
      }
}

// ---------------------------------------------------------------------------
// K2a: channel-mixing conv (1x3 along w) on q/k/v lin outputs. lin3/conv3 = [p][b][c][f][w] bf16
__global__ __launch_bounds__(256) void conv_kernel(
    const u16* __restrict__ lin3, u16* __restrict__ conv3,
    const float* __restrict__ wqc, const float* __restrict__ wkc, const float* __restrict__ wvc,
    const float* __restrict__ bq, const float* __restrict__ bk, const float* __restrict__ bv) {
  int w = blockIdx.x * 256 + threadIdx.x;
  int f = blockIdx.y;
  int b = blockIdx.z;
  const float* wcs[3] = {wqc, wkc, wvc};
  const float* bs[3] = {bq, bk, bv};
#pragma unroll
  for (int p = 0; p < 3; p++) {
    const float* wc = wcs[p];
    float acc[4];
#pragma unroll
    for (int o = 0; o < 4; o++) acc[o] = bs[p][o];
#pragma unroll
    for (int i = 0; i < 4; i++) {
      size_t base = ((size_t)((p * 2 + b) * 4 + i) * Fn + f) * Wn + w;
      float xm = (w > 0) ? bf2f(lin3[base - 1]) : 0.f;
      float x0 = bf2f(lin3[base]);
      float xp = (w < Wn - 1) ? bf2f(lin3[base + 1]) : 0.f;
#pragma unroll
      for (int o = 0; o < 4; o++) {
        const float* wr = wc + (o * 4 + i) * 3;
        acc[o] += wr[0] * xm + wr[1] * x0 + wr[2] * xp;
      }
    }
#pragma unroll
    for (int o = 0; o < 4; o++)
      conv3[((size_t)((p * 2 + b) * 4 + o) * Fn + f) * Wn + w] = f2bf(acc[o]);
  }
}

// ---------------------------------------------------------------------------
// K2b: heads + rotary + transpose: conv[q|k][b,c,h*64+d,w] -> Q/K [b,c,h,w,d] bf16
__global__ __launch_bounds__(256) void rot_kernel(
    const u16* __restrict__ conv3, u16* __restrict__ Qb, u16* __restrict__ Kb) {
  __shared__ __align__(16) u16 T[64 * 72];       // [d][w_local] pad 8
  int w0 = blockIdx.x * 64;
  int t = blockIdx.y >> 3;                        // 0=q 1=k
  int h = blockIdx.y & 7;
  int bc = blockIdx.z;                            // b*4+c
  int b = bc >> 2, c = bc & 3;
  const u16* src = conv3 + ((size_t)((t * 2 + b) * 4 + c) * Fn + h * 64) * Wn;
  int tid = threadIdx.x;
  {
    int dl = tid >> 2, g = tid & 3;
    const u16* s = src + (size_t)dl * Wn + w0 + g * 16;
    *(uint4*)&T[dl * 72 + g * 16] = *(const uint4*)(s);
    *(uint4*)&T[dl * 72 + g * 16 + 8] = *(const uint4*)(s + 8);
  }
  __syncthreads();
  int wl = tid >> 2, dg = tid & 3;
  int pos = w0 + wl;
  u16 ov[16];
#pragma unroll
  for (int u = 0; u < 16; u += 2) {
    int d = dg * 16 + u;
    float x0 = bf2f(T[d * 72 + wl]);
    float x1 = bf2f(T[(d + 1) * 72 + wl]);
    float inv = exp2f(-(float)d * (13.287712379549449f / 64.f));  // 10000^(-d/64)
    float th = (float)pos * inv;
    float sn, cs;
    sincosf(th, &sn, &cs);
    ov[u] = f2bf(x0 * cs - x1 * sn);
    ov[u + 1] = f2bf(x1 * cs + x0 * sn);
  }
  u16* dst = (t == 0 ? Qb : Kb) + ((size_t)(bc * 8 + h) * Wn + pos) * 64 + dg * 16;
  uint4 o0, o1;
  o0.x = pack2(ov[0], ov[1]);  o0.y = pack2(ov[2], ov[3]);
  o0.z = pack2(ov[4], ov[5]);  o0.w = pack2(ov[6], ov[7]);
  o1.x = pack2(ov[8], ov[9]);  o1.y = pack2(ov[10], ov[11]);
  o1.z = pack2(ov[12], ov[13]); o1.w = pack2(ov[14], ov[15]);
  *(uint4*)(dst) = o0;
  *(uint4*)(dst + 8) = o1;
}

// ---------------------------------------------------------------------------
// K3: fused attention. Per (b,c,h, 128-q tile): S=QK^T (MFMA), t=S/sqrt(512)+prev+mask,
// write qk out, online softmax, P->LDS, PV (MFMA). Also writes A as [b,c,w,f] bf16.
__global__ __launch_bounds__(256) void attn_kernel(
    const u16* __restrict__ Qb, const u16* __restrict__ Kb, const u16* __restrict__ Vt,
    const float* __restrict__ prev, const float* __restrict__ maskp,
    float* __restrict__ qkp, u16* __restrict__ Abuf) {
  __shared__ __align__(16) u16 Ks[128 * 72];     // [k][d] pad 8
  __shared__ __align__(16) u16 Vs[64 * 136];     // [d][k] pad 8
  __shared__ __align__(16) u16 Ps[128 * 136];    // [q][k] pad 8
  const int bch = blockIdx.y;                     // (b*4+c)*8+h
  const int q0 = blockIdx.x * 128;
  const u16* Qg = Qb + (size_t)bch * 65536;
  const u16* Kg = Kb + (size_t)bch * 65536;
  const u16* Vg = Vt + (size_t)bch * 65536;      // conv_v: [d][w] == V^T, no transform needed
  const float* prevb = prev + (size_t)bch * 1048576;
  float* qkb = qkp + (size_t)bch * 1048576;
  int tid = threadIdx.x, wave = tid >> 6, lane = tid & 63;
  int quad = lane >> 4, l16 = lane & 15;
  const float SCALE = 0.044194173824159216f;     // 1/sqrt(512)

  short8 qf[2][2];
#pragma unroll
  for (int rt = 0; rt < 2; rt++)
#pragma unroll
    for (int ks = 0; ks < 2; ks++)
      qf[rt][ks] = *(const short8*)(Qg + (size_t)(q0 + wave * 32 + rt * 16 + l16) * 64 + ks * 32 + quad * 8);

  f32x4 oa[2][4];
  float m_run[2][4], l_run[2][4];
#pragma unroll
  for (int rt = 0; rt < 2; rt++)
#pragma unroll
    for (int j = 0; j < 4; j++) {
      oa[rt][j] = (f32x4){0.f, 0.f, 0.f, 0.f};
      m_run[rt][j] = -INFINITY; l_run[rt][j] = 0.f;
    }

  for (int kt = 0; kt < 8; kt++) {
    int k0 = kt * 128;
    __syncthreads();                              // protect Ks/Vs/Ps reuse
#pragma unroll
    for (int t = 0; t < 4; t++) {
      int c = tid + 256 * t;
      { int r = c >> 3, of = c & 7;
        *(uint4*)&Ks[r * 72 + of * 8] = *(const uint4*)(Kg + (size_t)(k0 + r) * 64 + of * 8); }
      { int r = c >> 4, of = c & 15;
        *(uint4*)&Vs[r * 136 + of * 8] = *(const uint4*)(Vg + (size_t)r * Wn + k0 + of * 8); }
    }
    __syncthreads();

    f32x4 s[2][8];
#pragma unroll
    for (int rt = 0; rt < 2; rt++)
#pragma unroll
      for (int ct = 0; ct < 8; ct++) s[rt][ct] = (f32x4){0.f, 0.f, 0.f, 0.f};
#pragma unroll
    for (int ct = 0; ct < 8; ct++) {
#pragma unroll
      for (int ks = 0; ks < 2; ks++) {
        short8 kf = *(const short8*)&Ks[(ct * 16 + l16) * 72 + ks * 32 + quad * 8];
        s[0][ct] = __builtin_amdgcn_mfma_f32_16x16x32_bf16(qf[0][ks], kf, s[0][ct], 0, 0, 0);
        s[1][ct] = __builtin_amdgcn_mfma_f32_16x16x32_bf16(qf[1][ks], kf, s[1][ct], 0, 0, 0);
      }
    }
    // epilogue of S: add prev+mask, emit qk, online softmax, stage P
#pragma unroll
    for (int rt = 0; rt < 2; rt++) {
#pragma unroll
      for (int reg = 0; reg < 4; reg++) {
        int rloc = wave * 32 + rt * 16 + quad * 4 + reg;
        int rg = q0 + rloc;
        const float* pr = prevb + (size_t)rg * Wn + k0 + l16;
        const float* mr = maskp + (size_t)rg * Wn + k0 + l16;
        float* qr = qkb + (size_t)rg * Wn + k0 + l16;
        float tv[8];
#pragma unroll
        for (int ct = 0; ct < 8; ct++) {
          tv[ct] = s[rt][ct][reg] * SCALE + pr[ct * 16] + mr[ct * 16];
          qr[ct * 16] = tv[ct];
        }
        float mx = tv[0];
#pragma unroll
        for (int ct = 1; ct < 8; ct++) mx = fmaxf(mx, tv[ct]);
#pragma unroll
        for (int d = 1; d < 16; d <<= 1) mx = fmaxf(mx, __shfl_xor(mx, d));
        float mn = fmaxf(m_run[rt][reg], mx);
        float alpha = __expf(m_run[rt][reg] - mn);
        m_run[rt][reg] = mn;
        float rs = 0.f;
        int prow = rloc * 136;
#pragma unroll
        for (int ct = 0; ct < 8; ct++) {
          float pv = __expf(tv[ct] - mn);
          rs += pv;
          Ps[prow + ct * 16 + l16] = f2bf(pv);
        }
#pragma unroll
        for (int d = 1; d < 16; d <<= 1) rs += __shfl_xor(rs, d);
        l_run[rt][reg] = l_run[rt][reg] * alpha + rs;
#pragma unroll
        for (int jd = 0; jd < 4; jd++) oa[rt][jd][reg] *= alpha;
      }
    }
    __syncthreads();
    // PV: O += P(128-wide) * V
#pragma unroll
    for (int ks = 0; ks < 4; ks++) {
      short8 pf0 = *(const short8*)&Ps[(wave * 32 + 0 + l16) * 136 + ks * 32 + quad * 8];
      short8 pf1 = *(const short8*)&Ps[(wave * 32 + 16 + l16) * 136 + ks * 32 + quad * 8];
#pragma unroll
      for (int jd = 0; jd < 4; jd++) {
        short8 vf = *(const short8*)&Vs[(jd * 16 + l16) * 136 + ks * 32 + quad * 8];
        oa[0][jd] = __builtin_amdgcn_mfma_f32_16x16x32_bf16(pf0, vf, oa[0][jd], 0, 0, 0);
        oa[1][jd] = __builtin_amdgcn_mfma_f32_16x16x32_bf16(pf1, vf, oa[1][jd], 0, 0, 0);
      }
    }
  }
  // write A [b,c,w,f] bf16, f = h*64+d
  int bc = bch >> 3, h = bch & 7;
#pragma unroll
  for (int rt = 0; rt < 2; rt++)
#pragma unroll
    for (int reg = 0; reg < 4; reg++) {
      int rg = q0 + wave * 32 + rt * 16 + quad * 4 + reg;
      float inv_l = 1.f / l_run[rt][reg];
      u16* dst = Abuf + ((size_t)bc * Wn + rg) * Fn + h * 64 + l16;
#pragma unroll
      for (int jd = 0; jd < 4; jd++)
        dst[jd * 16] = f2bf(oa[rt][jd][reg] * inv_l);
    }
}

// ---------------------------------------------------------------------------
extern "C" void kernel_launch(void* const* d_in, const int* in_sizes, int n_in,
                              void* d_out, int out_size, void* d_ws, size_t ws_size,
                              hipStream_t stream) {
  (void)in_sizes; (void)n_in; (void)out_size; (void)ws_size;
  const float* x       = (const float*)d_in[0];
  const float* prev    = (const float*)d_in[1];
  const float* mask    = (const float*)d_in[2];
  const float* wq_lin  = (const float*)d_in[3];
  const float* wq_conv = (const float*)d_in[4];
  const float* bq      = (const float*)d_in[5];
  const float* wk_lin  = (const float*)d_in[6];
  const float* wk_conv = (const float*)d_in[7];
  const float* bk      = (const float*)d_in[8];
  const float* wv_lin  = (const float*)d_in[9];
  const float* wv_conv = (const float*)d_in[10];
  const float* bv      = (const float*)d_in[11];
  const float* wo_lin  = (const float*)d_in[12];

  float* outp = (float*)d_out;                   // [B,C,F,W] fp32 = 4194304
  float* qkp  = outp + (size_t)BCFW;             // [B,C,H,W,W] fp32 = 67108864

  char* ws = (char*)d_ws;
  u16* xTb   = (u16*)(ws + 0);                   //  8 MB: [b,c,w,f] bf16
  u16* wb3   = (u16*)(ws + ((size_t)8 << 20));   //  6 MB: [q,k,v][c][g][f] bf16
  u16* wob   = (u16*)(ws + ((size_t)14 << 20));  //  2 MB: [c][g][f] bf16
  u16* lin3  = (u16*)(ws + ((size_t)16 << 20));  // 24 MB: [p][b][c][f][w] bf16
  u16* conv3 = (u16*)(ws + ((size_t)40 << 20));  // 24 MB: same layout
  u16* Qbuf  = lin3;                             // reuse lin3 region after conv
  u16* Kbuf  = lin3 + (size_t)BCFW;
  u16* Abuf  = lin3 + (size_t)2 * BCFW;
  u16* Vt    = conv3 + (size_t)2 * BCFW;         // conv_v doubles as V^T [b,c,h,d,w]

  wconv_kernel<<<4096, 256, 0, stream>>>(wq_lin, wk_lin, wv_lin, wo_lin, wb3, wob);
  xT_kernel<<<dim3(16, 8, 8), 256, 0, stream>>>(x, xTb);
  gemm_bt_kernel<<<dim3(32, 8, 3), 256, 0, stream>>>(wb3, xTb, lin3, nullptr);
  conv_kernel<<<dim3(4, 512, 2), 256, 0, stream>>>(lin3, conv3, wq_conv, wk_conv, wv_conv, bq, bk, bv);
  rot_kernel<<<dim3(16, 16, 8), 256, 0, stream>>>(conv3, Qbuf, Kbuf);
  attn_kernel<<<dim3(8, 64), 256, 0, stream>>>(Qbuf, Kbuf, Vt, prev, mask, qkp, Abuf);
  gemm_bt_kernel<<<dim3(32, 8, 1), 256, 0, stream>>>(wob, Abuf, nullptr, outp);
}

// Round 2
// 688.005 us; speedup vs baseline: 1.2046x; 1.2046x over previous
//
#include <hip/hip_runtime.h>
#include <hip/hip_bf16.h>
#include <math.h>

typedef unsigned short u16;
typedef unsigned int   u32;
typedef __attribute__((ext_vector_type(8))) short short8;  // 8 bf16 (4 VGPRs) - MFMA A/B frag
typedef __attribute__((ext_vector_type(4))) float f32x4;   // MFMA C/D frag

#define Bn 2
#define Cn 4
#define Fn 512
#define Hn 8
#define Wn 1024
#define DHn 64
#define FW (Fn*Wn)            // 524288 per (b,c)
#define BCFW (Bn*Cn*Fn*Wn)    // 4194304 per tensor

__device__ __forceinline__ u16 f2bf(float f) {
  u32 u = __builtin_bit_cast(u32, f);
  u += 0x7fffu + ((u >> 16) & 1u);   // round-to-nearest-even
  return (u16)(u >> 16);
}
__device__ __forceinline__ float bf2f(u16 h) {
  u32 u = ((u32)h) << 16;
  return __builtin_bit_cast(float, u);
}
__device__ __forceinline__ u32 pack2(u16 a, u16 b) { return (u32)a | ((u32)b << 16); }

// ---------------------------------------------------------------------------
// K0a: convert 4 linear-weight tensors fp32 -> bf16.  wb3 = [q,k,v][C][F][F], wob = [C][F][F]
__global__ __launch_bounds__(256) void wconv_kernel(
    const float* __restrict__ wq, const float* __restrict__ wk,
    const float* __restrict__ wv, const float* __restrict__ wo,
    u16* __restrict__ wb3, u16* __restrict__ wob) {
  int g = blockIdx.x * 256 + threadIdx.x;        // group of 4 elements
  int t = g >> 18;                                // tensor id (2^18 groups = 1M elems each)
  int off = (g & 0x3FFFF) * 4;
  const float* src = (t == 0) ? wq : (t == 1) ? wk : (t == 2) ? wv : wo;
  float4 v = *(const float4*)(src + off);
  u16* dst = (t < 3) ? (wb3 + (size_t)t * 1048576 + off) : (wob + off);
  uint2 p;
  p.x = pack2(f2bf(v.x), f2bf(v.y));
  p.y = pack2(f2bf(v.z), f2bf(v.w));
  *(uint2*)dst = p;
}

// ---------------------------------------------------------------------------
// K0b: x [b,c,f,w] fp32 -> xT [b,c,w,f] bf16 (K-contiguous for gemm_bt B-operand)
__global__ __launch_bounds__(256) void xT_kernel(const float* __restrict__ x, u16* __restrict__ xT) {
  __shared__ __align__(16) u16 T[64 * 72];       // [f_local][w_local], pad 8
  int w0 = blockIdx.x * 64, f0 = blockIdx.y * 64, bc = blockIdx.z;
  int tid = threadIdx.x;
  int r = tid >> 2, g = tid & 3;                  // r: f row, g: 16-col group
  const float* src = x + ((size_t)(bc * Fn + f0 + r)) * Wn + w0 + g * 16;
#pragma unroll
  for (int u = 0; u < 4; u++) {
    float4 v = *(const float4*)(src + u * 4);
    int cb = g * 16 + u * 4;
    T[r * 72 + cb + 0] = f2bf(v.x);
    T[r * 72 + cb + 1] = f2bf(v.y);
    T[r * 72 + cb + 2] = f2bf(v.z);
    T[r * 72 + cb + 3] = f2bf(v.w);
  }
  __syncthreads();
  int wl = tid >> 2, fg = tid & 3;
  u16 ov[16];
#pragma unroll
  for (int u = 0; u < 16; u++) ov[u] = T[(fg * 16 + u) * 72 + wl];
  u16* dst = xT + ((size_t)(bc * Wn + w0 + wl)) * Fn + f0 + fg * 16;
  uint4 o0, o1;
  o0.x = pack2(ov[0], ov[1]);  o0.y = pack2(ov[2], ov[3]);
  o0.z = pack2(ov[4], ov[5]);  o0.w = pack2(ov[6], ov[7]);
  o1.x = pack2(ov[8], ov[9]);  o1.y = pack2(ov[10], ov[11]);
  o1.z = pack2(ov[12], ov[13]); o1.w = pack2(ov[14], ov[15]);
  *(uint4*)(dst) = o0;
  *(uint4*)(dst + 8) = o1;
}

// ---------------------------------------------------------------------------
// GEMM: C[m][n] = sum_k A[m][k]*BT[n][k].  M=512,N=1024,K=512. 128x128 tile, BK=32.
// A = weights base [z][C][512][512]; BT base [bc][1024][512]. Cb bf16 or Cf fp32 out.
__global__ __launch_bounds__(256) void gemm_bt_kernel(
    const u16* __restrict__ Abase, const u16* __restrict__ BTbase,
    u16* __restrict__ Cb, float* __restrict__ Cf) {
  __shared__ __align__(16) u16 As[128 * 40];     // [128][32] pad->40
  __shared__ __align__(16) u16 Bs[128 * 40];
  int tile = blockIdx.x;                          // 0..31
  int bc = blockIdx.y;                            // 0..7 = b*4+c
  int p = blockIdx.z;
  int m0 = (tile & 3) * 128, n0 = (tile >> 2) * 128;
  const u16* A = Abase + ((size_t)(p * 4 + (bc & 3))) * (512 * 512) + (size_t)m0 * 512;
  const u16* BT = BTbase + (size_t)bc * (1024 * 512) + (size_t)n0 * 512;
  int tid = threadIdx.x, wave = tid >> 6, lane = tid & 63;
  int quad = lane >> 4, l16 = lane & 15;
  int wm = (wave >> 1) * 64, wn = (wave & 1) * 64;
  f32x4 acc[4][4];
#pragma unroll
  for (int i = 0; i < 4; i++)
#pragma unroll
    for (int j = 0; j < 4; j++) acc[i][j] = (f32x4){0.f, 0.f, 0.f, 0.f};
  for (int k0 = 0; k0 < 512; k0 += 32) {
    __syncthreads();
    {
      int c0 = tid, c1 = tid + 256;
      int r = c0 >> 2, o = c0 & 3;
      *(uint4*)&As[r * 40 + o * 8] = *(const uint4*)(A + (size_t)r * 512 + k0 + o * 8);
      *(uint4*)&Bs[r * 40 + o * 8] = *(const uint4*)(BT + (size_t)r * 512 + k0 + o * 8);
      r = c1 >> 2; o = c1 & 3;
      *(uint4*)&As[r * 40 + o * 8] = *(const uint4*)(A + (size_t)r * 512 + k0 + o * 8);
      *(uint4*)&Bs[r * 40 + o * 8] = *(const uint4*)(BT + (size_t)r * 512 + k0 + o * 8);
    }
    __syncthreads();
    short8 af[4], bfr[4];
#pragma unroll
    for (int i = 0; i < 4; i++) af[i] = *(const short8*)&As[(wm + i * 16 + l16) * 40 + quad * 8];
#pragma unroll
    for (int j = 0; j < 4; j++) bfr[j] = *(const short8*)&Bs[(wn + j * 16 + l16) * 40 + quad * 8];
#pragma unroll
    for (int i = 0; i < 4; i++)
#pragma unroll
      for (int j = 0; j < 4; j++)
        acc[i][j] = __builtin_amdgcn_mfma_f32_16x16x32_bf16(af[i], bfr[j], acc[i][j], 0, 0, 0);
  }
  size_t coff = (size_t)(Cb ? (p * 8 + bc) : bc) * FW;
#pragma unroll
  for (int i = 0; i < 4; i++)
#pragma unroll
    for (int j = 0; j < 4; j++)
#pragma unroll
      for (int reg = 0; reg < 4; reg++) {
        int row = m0 + wm + i * 16 + quad * 4 + reg;
        int col = n0 + wn + j * 16 + l16;
        if (Cb) Cb[coff + (size_t)row * 1024 + col] = f2bf(acc[i][j][reg]);
        else    Cf[coff + (size_t)row * 1024 + col] = acc[i][j][reg];
      }
}

// ---------------------------------------------------------------------------
// K2a: channel-mixing conv (1x3 along w) on q/k/v lin outputs. lin3/conv3 = [p][b][c][f][w] bf16
__global__ __launch_bounds__(256) void conv_kernel(
    const u16* __restrict__ lin3, u16* __restrict__ conv3,
    const float* __restrict__ wqc, const float* __restrict__ wkc, const float* __restrict__ wvc,
    const float* __restrict__ bq, const float* __restrict__ bk, const float* __restrict__ bv) {
  int w = blockIdx.x * 256 + threadIdx.x;
  int f = blockIdx.y;
  int b = blockIdx.z;
  const float* wcs[3] = {wqc, wkc, wvc};
  const float* bs[3] = {bq, bk, bv};
#pragma unroll
  for (int p = 0; p < 3; p++) {
    const float* wc = wcs[p];
    float acc[4];
#pragma unroll
    for (int o = 0; o < 4; o++) acc[o] = bs[p][o];
#pragma unroll
    for (int i = 0; i < 4; i++) {
      size_t base = ((size_t)((p * 2 + b) * 4 + i) * Fn + f) * Wn + w;
      float xm = (w > 0) ? bf2f(lin3[base - 1]) : 0.f;
      float x0 = bf2f(lin3[base]);
      float xp = (w < Wn - 1) ? bf2f(lin3[base + 1]) : 0.f;
#pragma unroll
      for (int o = 0; o < 4; o++) {
        const float* wr = wc + (o * 4 + i) * 3;
        acc[o] += wr[0] * xm + wr[1] * x0 + wr[2] * xp;
      }
    }
#pragma unroll
    for (int o = 0; o < 4; o++)
      conv3[((size_t)((p * 2 + b) * 4 + o) * Fn + f) * Wn + w] = f2bf(acc[o]);
  }
}

// ---------------------------------------------------------------------------
// K2b: heads + rotary + transpose: conv[q|k][b,c,h*64+d,w] -> Q/K [b,c,h,w,d] bf16
__global__ __launch_bounds__(256) void rot_kernel(
    const u16* __restrict__ conv3, u16* __restrict__ Qb, u16* __restrict__ Kb) {
  __shared__ __align__(16) u16 T[64 * 72];       // [d][w_local] pad 8
  int w0 = blockIdx.x * 64;
  int t = blockIdx.y >> 3;                        // 0=q 1=k
  int h = blockIdx.y & 7;
  int bc = blockIdx.z;                            // b*4+c
  int b = bc >> 2, c = bc & 3;
  const u16* src = conv3 + ((size_t)((t * 2 + b) * 4 + c) * Fn + h * 64) * Wn;
  int tid = threadIdx.x;
  {
    int dl = tid >> 2, g = tid & 3;
    const u16* s = src + (size_t)dl * Wn + w0 + g * 16;
    *(uint4*)&T[dl * 72 + g * 16] = *(const uint4*)(s);
    *(uint4*)&T[dl * 72 + g * 16 + 8] = *(const uint4*)(s + 8);
  }
  __syncthreads();
  int wl = tid >> 2, dg = tid & 3;
  int pos = w0 + wl;
  u16 ov[16];
#pragma unroll
  for (int u = 0; u < 16; u += 2) {
    int d = dg * 16 + u;
    float x0 = bf2f(T[d * 72 + wl]);
    float x1 = bf2f(T[(d + 1) * 72 + wl]);
    float inv = exp2f(-(float)d * (13.287712379549449f / 64.f));  // 10000^(-d/64)
    float th = (float)pos * inv;
    float sn, cs;
    sincosf(th, &sn, &cs);
    ov[u] = f2bf(x0 * cs - x1 * sn);
    ov[u + 1] = f2bf(x1 * cs + x0 * sn);
  }
  u16* dst = (t == 0 ? Qb : Kb) + ((size_t)(bc * 8 + h) * Wn + pos) * 64 + dg * 16;
  uint4 o0, o1;
  o0.x = pack2(ov[0], ov[1]);  o0.y = pack2(ov[2], ov[3]);
  o0.z = pack2(ov[4], ov[5]);  o0.w = pack2(ov[6], ov[7]);
  o1.x = pack2(ov[8], ov[9]);  o1.y = pack2(ov[10], ov[11]);
  o1.z = pack2(ov[12], ov[13]); o1.w = pack2(ov[14], ov[15]);
  *(uint4*)(dst) = o0;
  *(uint4*)(dst + 8) = o1;
}

// ---------------------------------------------------------------------------
// K3a: qk materialization + softmax partial stats.
// Per (64-q tile, 128-k tile, bch): S = QK^T * scale via MFMA -> LDS fp32 ->
// vectorized pass adds prev+mask, writes qk (fp32, dwordx4), computes per-row
// partial (max, sumexp) for this k-tile -> stats[bch][q][kt] = float2(m, l).
__global__ __launch_bounds__(256) void qk_kernel(
    const u16* __restrict__ Qb, const u16* __restrict__ Kb,
    const float* __restrict__ prev, const float* __restrict__ maskp,
    float* __restrict__ qkp, float2* __restrict__ stats) {
  __shared__ __align__(16) u16 Ks[128 * 72];     // [k][d] pad 8  (18.4 KB)
  __shared__ __align__(16) float Sf[64 * 132];   // [q][k] pad 4  (33.8 KB)
  const int q0 = blockIdx.x * 64;
  const int kt = blockIdx.y;
  const int k0 = kt * 128;
  const int bch = blockIdx.z;
  const u16* Qg = Qb + (size_t)bch * 65536;
  const u16* Kg = Kb + (size_t)bch * 65536;
  const float* prevb = prev + (size_t)bch * 1048576;
  float* qkb = qkp + (size_t)bch * 1048576;
  int tid = threadIdx.x, wave = tid >> 6, lane = tid & 63;
  int quad = lane >> 4, l16 = lane & 15;
  const float SCALE = 0.044194173824159216f;     // 1/sqrt(512)

  // Q frags: wave w owns q rows [q0 + w*16, +16)
  short8 qf[2];
#pragma unroll
  for (int ks = 0; ks < 2; ks++)
    qf[ks] = *(const short8*)(Qg + (size_t)(q0 + wave * 16 + l16) * 64 + ks * 32 + quad * 8);

  // stage K tile
#pragma unroll
  for (int t = 0; t < 4; t++) {
    int c = tid + 256 * t;
    int r = c >> 3, o = c & 7;
    *(uint4*)&Ks[r * 72 + o * 8] = *(const uint4*)(Kg + (size_t)(k0 + r) * 64 + o * 8);
  }
  __syncthreads();

  f32x4 acc[8];
#pragma unroll
  for (int ct = 0; ct < 8; ct++) acc[ct] = (f32x4){0.f, 0.f, 0.f, 0.f};
#pragma unroll
  for (int ct = 0; ct < 8; ct++)
#pragma unroll
    for (int ks = 0; ks < 2; ks++) {
      short8 kf = *(const short8*)&Ks[(ct * 16 + l16) * 72 + ks * 32 + quad * 8];
      acc[ct] = __builtin_amdgcn_mfma_f32_16x16x32_bf16(qf[ks], kf, acc[ct], 0, 0, 0);
    }

  // scatter S*scale to LDS (C-layout: row = wave*16+quad*4+reg, col = ct*16+l16)
#pragma unroll
  for (int ct = 0; ct < 8; ct++)
#pragma unroll
    for (int reg = 0; reg < 4; reg++)
      Sf[(wave * 16 + quad * 4 + reg) * 132 + ct * 16 + l16] = acc[ct][reg] * SCALE;
  __syncthreads();

  // vectorized pass: thread -> row r = tid>>2, cols (tid&3)*32 .. +32
  int r = tid >> 2, c0 = (tid & 3) * 32;
  const float* pr = prevb + (size_t)(q0 + r) * Wn + k0 + c0;
  const float* mr = maskp + (size_t)(q0 + r) * Wn + k0 + c0;
  float* qr = qkb + (size_t)(q0 + r) * Wn + k0 + c0;
  float tv[32];
  float mx = -INFINITY;
#pragma unroll
  for (int u = 0; u < 8; u++) {
    float4 s4 = *(const float4*)&Sf[r * 132 + c0 + u * 4];
    float4 p4 = *(const float4*)(pr + u * 4);
    float4 m4 = *(const float4*)(mr + u * 4);
    float4 t4;
    t4.x = s4.x + p4.x + m4.x;  t4.y = s4.y + p4.y + m4.y;
    t4.z = s4.z + p4.z + m4.z;  t4.w = s4.w + p4.w + m4.w;
    *(float4*)(qr + u * 4) = t4;
    tv[u * 4 + 0] = t4.x; tv[u * 4 + 1] = t4.y; tv[u * 4 + 2] = t4.z; tv[u * 4 + 3] = t4.w;
    mx = fmaxf(mx, fmaxf(fmaxf(t4.x, t4.y), fmaxf(t4.z, t4.w)));
  }
  // row spans 4 consecutive lanes (tid&3)
  mx = fmaxf(mx, __shfl_xor(mx, 1));
  mx = fmaxf(mx, __shfl_xor(mx, 2));
  float sum = 0.f;
#pragma unroll
  for (int u = 0; u < 32; u++) sum += __expf(tv[u] - mx);
  sum += __shfl_xor(sum, 1);
  sum += __shfl_xor(sum, 2);
  if ((tid & 3) == 0)
    stats[((size_t)bch * Wn + q0 + r) * 8 + kt] = make_float2(mx, sum);
}

// ---------------------------------------------------------------------------
// K3b: PV. Per (64-q tile, bch): combine stats -> (M, 1/L); stream qk fp32,
// p = exp(t - M) / L -> bf16 LDS; V -> LDS; MFMA accumulate; write A [b,c,w,f].
__global__ __launch_bounds__(256) void pv_kernel(
    const float* __restrict__ qkp, const u16* __restrict__ Vt,
    const float2* __restrict__ stats, u16* __restrict__ Abuf) {
  __shared__ __align__(16) u16 Ps[64 * 136];     // [q][k] pad 8 (17.4 KB)
  __shared__ __align__(16) u16 Vs[64 * 136];     // [d][k] pad 8 (17.4 KB)
  __shared__ float Mrow[64], Lrow[64];
  const int q0 = blockIdx.x * 64;
  const int bch = blockIdx.y;
  const float* qkb = qkp + (size_t)bch * 1048576;
  const u16* Vg = Vt + (size_t)bch * 65536;      // [d][w]
  int tid = threadIdx.x, wave = tid >> 6, lane = tid & 63;
  int quad = lane >> 4, l16 = lane & 15;

  if (tid < 64) {
    const float2* st = stats + ((size_t)bch * Wn + q0 + tid) * 8;
    float M = -INFINITY;
#pragma unroll
    for (int kt = 0; kt < 8; kt++) M = fmaxf(M, st[kt].x);
    float L = 0.f;
#pragma unroll
    for (int kt = 0; kt < 8; kt++) L += st[kt].y * __expf(st[kt].x - M);
    Mrow[tid] = M;
    Lrow[tid] = 1.f / L;
  }

  f32x4 oa[4];
#pragma unroll
  for (int jd = 0; jd < 4; jd++) oa[jd] = (f32x4){0.f, 0.f, 0.f, 0.f};

  int pr_ = tid >> 2, pc_ = (tid & 3) * 32;      // P staging assignment
  float Mr, Li;

  for (int kt = 0; kt < 8; kt++) {
    int k0 = kt * 128;
    __syncthreads();                              // Mrow/Lrow ready (kt=0); Ps/Vs free
    if (kt == 0) { Mr = Mrow[pr_]; Li = Lrow[pr_]; }
    // stage V tile: [d 64][k 128]
#pragma unroll
    for (int t = 0; t < 4; t++) {
      int c = tid + 256 * t;
      int r = c >> 4, o = c & 15;
      *(uint4*)&Vs[r * 136 + o * 8] = *(const uint4*)(Vg + (size_t)r * Wn + k0 + o * 8);
    }
    // stage P tile: thread -> row pr_, cols pc_..pc_+32
    const float* qr = qkb + (size_t)(q0 + pr_) * Wn + k0 + pc_;
#pragma unroll
    for (int u = 0; u < 8; u++) {
      float4 t4 = *(const float4*)(qr + u * 4);
      u16 p0 = f2bf(__expf(t4.x - Mr) * Li);
      u16 p1 = f2bf(__expf(t4.y - Mr) * Li);
      u16 p2 = f2bf(__expf(t4.z - Mr) * Li);
      u16 p3 = f2bf(__expf(t4.w - Mr) * Li);
      uint2 pk; pk.x = pack2(p0, p1); pk.y = pack2(p2, p3);
      *(uint2*)&Ps[pr_ * 136 + pc_ + u * 4] = pk;
    }
    __syncthreads();
    // PV MFMA: wave w -> q rows [w*16, +16)
#pragma unroll
    for (int ks = 0; ks < 4; ks++) {
      short8 pf = *(const short8*)&Ps[(wave * 16 + l16) * 136 + ks * 32 + quad * 8];
#pragma unroll
      for (int jd = 0; jd < 4; jd++) {
        short8 vf = *(const short8*)&Vs[(jd * 16 + l16) * 136 + ks * 32 + quad * 8];
        oa[jd] = __builtin_amdgcn_mfma_f32_16x16x32_bf16(pf, vf, oa[jd], 0, 0, 0);
      }
    }
  }
  // write A [b,c,w,f] bf16, f = h*64 + d. C-layout: row=wave*16+quad*4+reg, col=jd*16+l16
  int bc = bch >> 3, h = bch & 7;
#pragma unroll
  for (int reg = 0; reg < 4; reg++) {
    int rg = q0 + wave * 16 + quad * 4 + reg;
    u16* dst = Abuf + ((size_t)bc * Wn + rg) * Fn + h * 64 + l16;
#pragma unroll
    for (int jd = 0; jd < 4; jd++)
      dst[jd * 16] = f2bf(oa[jd][reg]);
  }
}

// ---------------------------------------------------------------------------
extern "C" void kernel_launch(void* const* d_in, const int* in_sizes, int n_in,
                              void* d_out, int out_size, void* d_ws, size_t ws_size,
                              hipStream_t stream) {
  (void)in_sizes; (void)n_in; (void)out_size; (void)ws_size;
  const float* x       = (const float*)d_in[0];
  const float* prev    = (const float*)d_in[1];
  const float* mask    = (const float*)d_in[2];
  const float* wq_lin  = (const float*)d_in[3];
  const float* wq_conv = (const float*)d_in[4];
  const float* bq      = (const float*)d_in[5];
  const float* wk_lin  = (const float*)d_in[6];
  const float* wk_conv = (const float*)d_in[7];
  const float* bk      = (const float*)d_in[8];
  const float* wv_lin  = (const float*)d_in[9];
  const float* wv_conv = (const float*)d_in[10];
  const float* bv      = (const float*)d_in[11];
  const float* wo_lin  = (const float*)d_in[12];

  float* outp = (float*)d_out;                   // [B,C,F,W] fp32 = 4194304
  float* qkp  = outp + (size_t)BCFW;             // [B,C,H,W,W] fp32 = 67108864

  char* ws = (char*)d_ws;
  u16* xTb   = (u16*)(ws + 0);                   //  8 MB: [b,c,w,f] bf16
  u16* wb3   = (u16*)(ws + ((size_t)8 << 20));   //  6 MB: [q,k,v][c][g][f] bf16
  u16* wob   = (u16*)(ws + ((size_t)14 << 20));  //  2 MB: [c][g][f] bf16
  u16* lin3  = (u16*)(ws + ((size_t)16 << 20));  // 24 MB: [p][b][c][f][w] bf16
  u16* conv3 = (u16*)(ws + ((size_t)40 << 20));  // 24 MB: same layout
  u16* Qbuf  = lin3;                             // reuse lin3 region after conv
  u16* Kbuf  = lin3 + (size_t)BCFW;
  u16* Abuf  = lin3 + (size_t)2 * BCFW;
  u16* Vt    = conv3 + (size_t)2 * BCFW;         // conv_v doubles as V^T [b,c,h,d,w]
  float2* stats = (float2*)(ws + ((size_t)40 << 20)); // 4 MB, aliases conv_q (free after rot)

  wconv_kernel<<<4096, 256, 0, stream>>>(wq_lin, wk_lin, wv_lin, wo_lin, wb3, wob);
  xT_kernel<<<dim3(16, 8, 8), 256, 0, stream>>>(x, xTb);
  gemm_bt_kernel<<<dim3(32, 8, 3), 256, 0, stream>>>(wb3, xTb, lin3, nullptr);
  conv_kernel<<<dim3(4, 512, 2), 256, 0, stream>>>(lin3, conv3, wq_conv, wk_conv, wv_conv, bq, bk, bv);
  rot_kernel<<<dim3(16, 16, 8), 256, 0, stream>>>(conv3, Qbuf, Kbuf);
  qk_kernel<<<dim3(16, 8, 64), 256, 0, stream>>>(Qbuf, Kbuf, prev, mask, qkp, stats);
  pv_kernel<<<dim3(16, 64), 256, 0, stream>>>(qkp, Vt, stats, Abuf);
  gemm_bt_kernel<<<dim3(32, 8, 1), 256, 0, stream>>>(wob, Abuf, nullptr, outp);
}